// Round 1
// baseline (2624.542 us; speedup 1.0000x reference)
//
#include <hip/hip_runtime.h>
#include <hip/hip_bf16.h>
#include <math.h>

// Problem constants
#define D_MODEL 2048
#define D_FF    8192
#define MTOK    8192        // 4*2048 tokens
#define GSIZE   64
#define QBF     127.0f
#define EPSQ    1e-5f
#define W_NUMEL (D_FF * D_MODEL)        // 16,777,216 for all three weights
#define W_INV_NUMEL (1.0f / 16777216.0f)

typedef unsigned short u16;
typedef __attribute__((ext_vector_type(8))) short short8;   // 8 bf16 (A/B frag)
typedef __attribute__((ext_vector_type(4))) float f32x4;    // C/D frag
typedef __attribute__((ext_vector_type(4))) unsigned int u32x4;
typedef __attribute__((ext_vector_type(4))) unsigned short u16x4;

// Async global->LDS, 16B per lane. LDS image must be linear in lane order.
__device__ __forceinline__ void gload_lds16(const void* g, void* l) {
    __builtin_amdgcn_global_load_lds(
        (const __attribute__((address_space(1))) unsigned int*)g,
        (__attribute__((address_space(3))) unsigned int*)l, 16, 0, 0);
}

// Bijective XCD-chunked block swizzle (m204): hw-id orig -> logical tile id,
// so each XCD's round-robin share becomes a contiguous logical range.
__device__ __forceinline__ void xcd_swizzle(int& bx, int& by, int gx, int gy) {
    int nwg  = gx * gy;
    int orig = by * gx + bx;
    int q = nwg >> 3, r = nwg & 7;
    int xcd = orig & 7, loc = orig >> 3;
    int swz = (xcd < r ? xcd * (q + 1) : r * (q + 1) + (xcd - r) * q) + loc;
    bx = swz % gx;
    by = swz / gx;
}

// Tile-swizzled element offset (u16 units) for logical (tileIdx, r, k):
//   off = tileIdx*8192 + r*64 + ((c ^ (r&7))*8) + j,  c=(k&63)>>3, j=k&7
// 128x64 bf16 tile = contiguous 16 KB block; XOR swizzle makes ds_read_b128
// fragment loads bank-conflict-free.

// ------- weight pack: fp32 [N,K] -> +-1 bf16 swizzled tiles, + mean|w| sum --
__global__ void wpack_kernel(const float* __restrict__ W, u16* __restrict__ Wb,
                             float* __restrict__ sumout, int N, int K) {
    const int Gk  = K >> 6;
    const int cpr = K >> 3;                 // 8-elem chunks per row
    int idx = blockIdx.x * blockDim.x + threadIdx.x;   // grid is exact
    int row = idx / cpr;
    int ck  = idx - row * cpr;
    int k0  = ck << 3;
    const float* src = W + (size_t)row * K + k0;
    f32x4 w0 = *(const f32x4*)src;
    f32x4 w1 = *(const f32x4*)(src + 4);
    unsigned hw[8];
    float s = 0.f;
    #pragma unroll
    for (int i = 0; i < 8; ++i) {
        float wv = (i < 4) ? w0[i] : w1[i - 4];
        s += fabsf(wv);
        hw[i] = (wv == 0.f) ? 0u : (0x3F80u | ((__float_as_uint(wv) >> 16) & 0x8000u));
    }
    u32x4 o;
    #pragma unroll
    for (int p = 0; p < 4; ++p) o[p] = hw[2 * p] | (hw[2 * p + 1] << 16);
    int nt = row >> 7, r = row & 127;
    int g = k0 >> 6, c8 = (k0 & 63) >> 3;
    size_t dst = ((size_t)(nt * Gk + g) << 13) + (size_t)r * 64 + (size_t)((c8 ^ (r & 7)) << 3);
    *(u32x4*)(Wb + dst) = o;
    // fused mean|w| reduction (weights read once instead of twice)
    #pragma unroll
    for (int off = 32; off > 0; off >>= 1) s += __shfl_xor(s, off);
    if ((threadIdx.x & 63) == 0) atomicAdd(sumout, s);
}

// ---------------- per-group activation quant (swizzled tile output) ------
// X: [M, K=Gk*64] fp32 -> Q int-valued-bf16 swizzled tiles, SdivT[g][M]=s/127
__global__ void quant_kernel(const float* __restrict__ X, u16* __restrict__ Q,
                             float* __restrict__ SdivT, int M, int Gk) {
    const int K = Gk << 6;
    const int lane = threadIdx.x & 63;
    const int segs = K >> 8;
    int widx = (blockIdx.x * blockDim.x + threadIdx.x) >> 6;
    if (widx >= M * segs) return;
    int row = widx / segs;
    int seg = widx - row * segs;
    int k0 = (seg << 8) + lane * 4;
    f32x4 v = *(const f32x4*)(X + (size_t)row * K + k0);
    float a = fmaxf(fmaxf(fabsf(v[0]), fabsf(v[1])), fmaxf(fabsf(v[2]), fabsf(v[3])));
    a = fmaxf(a, __shfl_xor(a, 1));
    a = fmaxf(a, __shfl_xor(a, 2));
    a = fmaxf(a, __shfl_xor(a, 4));
    a = fmaxf(a, __shfl_xor(a, 8));          // max over the 16-lane (64-elem) group
    float s = fmaxf(a, EPSQ);
    float rinv = QBF / s;
    u16x4 qo;
    #pragma unroll
    for (int c = 0; c < 4; ++c) {
        float q = rintf(fminf(fmaxf(v[c] * rinv, -QBF), QBF));
        qo[c] = (u16)(__float_as_uint(q) >> 16);                 // exact int bf16
    }
    int mt = row >> 7, r = row & 127;
    int gi = k0 >> 6;
    int c8 = (k0 & 63) >> 3;
    int j0 = k0 & 7;
    size_t dst = ((size_t)(mt * Gk + gi) << 13) + (size_t)r * 64
               + (size_t)((c8 ^ (r & 7)) << 3) + j0;
    *(u16x4*)(Q + dst) = qo;
    if ((lane & 15) == 0) SdivT[(size_t)gi * M + row] = s / QBF;
}

// ------------- fused up-projection: GEMM1+GEMM2 + silu*mul + requant -----
// Stages A once, both weight tiles; epilogue quantizes h per 64-col group
// (one wave's 64-col span == one quant group) and writes qh tiles + shT.
__global__ __launch_bounds__(256, 2)
void gemm_bit12(const u16* __restrict__ Aq, const float* __restrict__ SdivT,
                const u16* __restrict__ W1b, const u16* __restrict__ W2b,
                const float* __restrict__ wsum,
                u16* __restrict__ Qh, float* __restrict__ ShT,
                int G, int Mtot) {
    __shared__ __align__(16) u16 lsm[3 * 8192];   // lA | lB1 | lB2 (reused by epilogue)
    __shared__ __align__(16) float lS[128];
    u16* lA  = lsm;
    u16* lB1 = lsm + 8192;
    u16* lB2 = lsm + 16384;

    const int tid  = threadIdx.x;
    const int lane = tid & 63;
    const int wid  = tid >> 6;
    const int quad = lane >> 4;
    const int l16  = lane & 15;
    const int wm = (wid & 1) * 64;
    const int wn = (wid >> 1) * 64;

    int bx = blockIdx.x, by = blockIdx.y;
    xcd_swizzle(bx, by, gridDim.x, gridDim.y);
    const int m0 = by * 128;

    const char* gA  = (const char*)(Aq  + ((size_t)by * G << 13));
    const char* gB1 = (const char*)(W1b + ((size_t)bx * G << 13));
    const char* gB2 = (const char*)(W2b + ((size_t)bx * G << 13));
    char* dA  = (char*)lA  + tid * 16;
    char* dB1 = (char*)lB1 + tid * 16;
    char* dB2 = (char*)lB2 + tid * 16;

    f32x4 acc1[4][4], acc2[4][4];
    #pragma unroll
    for (int i = 0; i < 4; ++i)
        #pragma unroll
        for (int j = 0; j < 4; ++j) {
            acc1[i][j] = (f32x4){0.f, 0.f, 0.f, 0.f};
            acc2[i][j] = (f32x4){0.f, 0.f, 0.f, 0.f};
        }
    const f32x4 czero = {0.f, 0.f, 0.f, 0.f};

    for (int g = 0; g < G; ++g) {
        __syncthreads();                       // prior iter done reading LDS
        const char* sA  = gA  + ((size_t)g << 14);   // 16 KB per tile
        const char* sB1 = gB1 + ((size_t)g << 14);
        const char* sB2 = gB2 + ((size_t)g << 14);
        #pragma unroll
        for (int i = 0; i < 4; ++i) gload_lds16(sA  + tid * 16 + i * 4096, dA  + i * 4096);
        #pragma unroll
        for (int i = 0; i < 4; ++i) gload_lds16(sB1 + tid * 16 + i * 4096, dB1 + i * 4096);
        #pragma unroll
        for (int i = 0; i < 4; ++i) gload_lds16(sB2 + tid * 16 + i * 4096, dB2 + i * 4096);
        if (tid < 128) lS[tid] = SdivT[(size_t)g * Mtot + m0 + tid];
        __syncthreads();                       // drains vmcnt -> tiles visible

        short8 a[4][2];
        #pragma unroll
        for (int mi = 0; mi < 4; ++mi)
            #pragma unroll
            for (int ks = 0; ks < 2; ++ks) {
                int r = wm + mi * 16 + l16;
                int c = ks * 4 + quad;
                a[mi][ks] = *(const short8*)(lA + r * 64 + ((c ^ (r & 7)) << 3));
            }
        f32x4 sf[4];
        #pragma unroll
        for (int mi = 0; mi < 4; ++mi)
            sf[mi] = *(const f32x4*)(lS + wm + mi * 16 + quad * 4);

        #pragma unroll
        for (int ni = 0; ni < 4; ++ni) {
            int rb = wn + ni * 16 + l16;
            int sw0 = ((quad)     ^ (rb & 7)) << 3;
            int sw1 = ((4 + quad) ^ (rb & 7)) << 3;
            short8 b10 = *(const short8*)(lB1 + rb * 64 + sw0);
            short8 b11 = *(const short8*)(lB1 + rb * 64 + sw1);
            short8 b20 = *(const short8*)(lB2 + rb * 64 + sw0);
            short8 b21 = *(const short8*)(lB2 + rb * 64 + sw1);
            #pragma unroll
            for (int mi = 0; mi < 4; ++mi) {
                f32x4 t = __builtin_amdgcn_mfma_f32_16x16x32_bf16(a[mi][0], b10, czero, 0, 0, 0);
                t = __builtin_amdgcn_mfma_f32_16x16x32_bf16(a[mi][1], b11, t, 0, 0, 0);
                acc1[mi][ni] += t * sf[mi];
                f32x4 u = __builtin_amdgcn_mfma_f32_16x16x32_bf16(a[mi][0], b20, czero, 0, 0, 0);
                u = __builtin_amdgcn_mfma_f32_16x16x32_bf16(a[mi][1], b21, u, 0, 0, 0);
                acc2[mi][ni] += u * sf[mi];
            }
        }
    }

    // ---- epilogue: h = silu(y1)*y2, per-64-group quant, swizzled tile out ----
    const float ws1 = wsum[0] * W_INV_NUMEL;
    const float ws2 = wsum[1] * W_INV_NUMEL;
    const int gl    = wn >> 6;                 // which of the 2 groups in this block
    const int gbase = bx * 2;                  // global d_ff group base (128 cols/block)
    __syncthreads();                           // done with lA/lB*, reuse as staging
    #pragma unroll
    for (int mi = 0; mi < 4; ++mi) {
        #pragma unroll
        for (int rr = 0; rr < 4; ++rr) {
            float h[4];
            #pragma unroll
            for (int ni = 0; ni < 4; ++ni) {
                float y1 = acc1[mi][ni][rr] * ws1;
                float y2 = acc2[mi][ni][rr] * ws2;
                h[ni] = (y1 / (1.f + expf(-y1))) * y2;   // silu(y1)*y2
            }
            float am = fmaxf(fmaxf(fabsf(h[0]), fabsf(h[1])), fmaxf(fabsf(h[2]), fabsf(h[3])));
            am = fmaxf(am, __shfl_xor(am, 1));
            am = fmaxf(am, __shfl_xor(am, 2));
            am = fmaxf(am, __shfl_xor(am, 4));
            am = fmaxf(am, __shfl_xor(am, 8));   // absmax over 4 ni x 16 lanes = 64 cols
            float s = fmaxf(am, EPSQ);
            float rinv = QBF / s;
            int rblk = wm + mi * 16 + quad * 4 + rr;
            #pragma unroll
            for (int ni = 0; ni < 4; ++ni) {
                float qv = rintf(fminf(fmaxf(h[ni] * rinv, -QBF), QBF));
                int k = ni * 16 + l16;
                int c8 = k >> 3;
                lsm[gl * 8192 + rblk * 64 + ((c8 ^ (rblk & 7)) << 3) + (k & 7)]
                    = (u16)(__float_as_uint(qv) >> 16);
            }
            if (l16 == 0) ShT[(size_t)(gbase + gl) * Mtot + m0 + rblk] = s / QBF;
        }
    }
    __syncthreads();
    // two 16 KB tiles (groups gbase, gbase+1) are contiguous in Qh
    size_t base = ((size_t)by * 128 + (size_t)gbase) << 13;   // u16 elements; Gff=128
    u32x4* dst = (u32x4*)(Qh + base);
    const u32x4* src = (const u32x4*)lsm;
    #pragma unroll
    for (int i = 0; i < 8; ++i) dst[tid + i * 256] = src[tid + i * 256];
}

// ---------------- down-projection: split-K bit-GEMM, atomic epilogue ------
__global__ __launch_bounds__(256, 3)
void gemm_bit3(const u16* __restrict__ Aq, const float* __restrict__ SdivT,
               const u16* __restrict__ Wb, const float* __restrict__ wsum,
               float* __restrict__ Y, int N, int G, int Mtot, int gPer) {
    __shared__ __align__(16) u16  lA[8192];
    __shared__ __align__(16) u16  lB[8192];
    __shared__ __align__(16) float lS[128];

    const int tid  = threadIdx.x;
    const int lane = tid & 63;
    const int wid  = tid >> 6;
    const int quad = lane >> 4;
    const int l16  = lane & 15;
    const int wm = (wid & 1) * 64;
    const int wn = (wid >> 1) * 64;

    int bx = blockIdx.x, by = blockIdx.y;
    xcd_swizzle(bx, by, gridDim.x, gridDim.y);
    const int m0 = by * 128;
    const int n0 = bx * 128;
    const int g0 = blockIdx.z * gPer;

    const char* gA = (const char*)(Aq + ((size_t)by * G << 13));
    const char* gB = (const char*)(Wb + ((size_t)bx * G << 13));
    char* dA = (char*)lA + tid * 16;
    char* dB = (char*)lB + tid * 16;

    f32x4 acc[4][4];
    #pragma unroll
    for (int i = 0; i < 4; ++i)
        #pragma unroll
        for (int j = 0; j < 4; ++j) acc[i][j] = (f32x4){0.f, 0.f, 0.f, 0.f};
    const f32x4 czero = {0.f, 0.f, 0.f, 0.f};

    for (int g = g0; g < g0 + gPer; ++g) {
        __syncthreads();
        const char* sA = gA + ((size_t)g << 14);
        const char* sB = gB + ((size_t)g << 14);
        #pragma unroll
        for (int i = 0; i < 4; ++i) gload_lds16(sA + tid * 16 + i * 4096, dA + i * 4096);
        #pragma unroll
        for (int i = 0; i < 4; ++i) gload_lds16(sB + tid * 16 + i * 4096, dB + i * 4096);
        if (tid < 128) lS[tid] = SdivT[(size_t)g * Mtot + m0 + tid];
        __syncthreads();

        short8 a[4][2];
        #pragma unroll
        for (int mi = 0; mi < 4; ++mi)
            #pragma unroll
            for (int ks = 0; ks < 2; ++ks) {
                int r = wm + mi * 16 + l16;
                int c = ks * 4 + quad;
                a[mi][ks] = *(const short8*)(lA + r * 64 + ((c ^ (r & 7)) << 3));
            }
        f32x4 sf[4];
        #pragma unroll
        for (int mi = 0; mi < 4; ++mi)
            sf[mi] = *(const f32x4*)(lS + wm + mi * 16 + quad * 4);

        #pragma unroll
        for (int ni = 0; ni < 4; ++ni) {
            int rb = wn + ni * 16 + l16;
            short8 b0 = *(const short8*)(lB + rb * 64 + ((quad ^ (rb & 7)) << 3));
            short8 b1 = *(const short8*)(lB + rb * 64 + (((4 + quad) ^ (rb & 7)) << 3));
            #pragma unroll
            for (int mi = 0; mi < 4; ++mi) {
                f32x4 t = __builtin_amdgcn_mfma_f32_16x16x32_bf16(a[mi][0], b0, czero, 0, 0, 0);
                t = __builtin_amdgcn_mfma_f32_16x16x32_bf16(a[mi][1], b1, t, 0, 0, 0);
                acc[mi][ni] += t * sf[mi];
            }
        }
    }

    const float wsc = wsum[0] * W_INV_NUMEL;   // mean|w3| (wsum pre-offset by caller)
    #pragma unroll
    for (int mi = 0; mi < 4; ++mi) {
        #pragma unroll
        for (int ni = 0; ni < 4; ++ni) {
            int col = n0 + wn + ni * 16 + l16;
            #pragma unroll
            for (int r = 0; r < 4; ++r) {
                int row = m0 + wm + mi * 16 + quad * 4 + r;
                atomicAdd(&Y[(size_t)row * N + col], acc[mi][ni][r] * wsc);
            }
        }
    }
}

extern "C" void kernel_launch(void* const* d_in, const int* in_sizes, int n_in,
                              void* d_out, int out_size, void* d_ws, size_t ws_size,
                              hipStream_t stream) {
    const float* x  = (const float*)d_in[0];
    const float* w1 = (const float*)d_in[1];
    const float* w2 = (const float*)d_in[2];
    const float* w3 = (const float*)d_in[3];
    float* out = (float*)d_out;

    // ---- workspace layout: packed weights (fixed) + chunked activations ----
    char* ws = (char*)d_ws;
    const size_t wbBytes = (size_t)W_NUMEL * 2;        // 32 MB per packed weight
    float* wsum = (float*)ws;
    char* p = ws + 256;
    u16* w1b = (u16*)p;  p += wbBytes;
    u16* w2b = (u16*)p;  p += wbBytes;
    u16* w3b = (u16*)p;  p += wbBytes;
    size_t fixed = (size_t)(p - ws);

    // per-token: qx 4096 + sxT 128 + qh 16384 + shT 512 = 21,120 B (no fp32 h!)
    const size_t perTok = (size_t)D_MODEL * 2 + 32 * 4 + (size_t)D_FF * 2 + 128 * 4;
    int Mc = 1024;
    for (int cand = MTOK; cand >= 1024; cand >>= 1) {
        if (fixed + perTok * (size_t)cand <= ws_size) { Mc = cand; break; }
    }
    const int nChunks = MTOK / Mc;

    u16*   qx  = (u16*)p;         p += (size_t)Mc * D_MODEL * 2;
    float* sxT = (float*)p;       p += (size_t)Mc * 32 * 4;      // [32][Mc]
    u16*   qh  = (u16*)p;         p += (size_t)Mc * D_FF * 2;
    float* shT = (float*)p;                                      // [128][Mc]

    (void)hipMemsetAsync(wsum, 0, 64, stream);
    (void)hipMemsetAsync(out, 0, (size_t)out_size, stream);      // split-K accumulates

    // pack weights + fused mean|w| (weights read exactly once)
    wpack_kernel<<<W_NUMEL / 8 / 256, 256, 0, stream>>>(w1, w1b, wsum + 0, D_FF, D_MODEL);
    wpack_kernel<<<W_NUMEL / 8 / 256, 256, 0, stream>>>(w2, w2b, wsum + 1, D_FF, D_MODEL);
    wpack_kernel<<<W_NUMEL / 8 / 256, 256, 0, stream>>>(w3, w3b, wsum + 2, D_MODEL, D_FF);

    const int S = (MTOK / Mc > 8192 / Mc) ? 8192 / Mc : 8192 / Mc;  // 8192/Mc: 1..8
    const int gPer = (D_FF / GSIZE) / S;                            // 128/S, exact

    for (int c = 0; c < nChunks; ++c) {
        const float* xc = x + (size_t)c * Mc * D_MODEL;
        float* outc     = out + (size_t)c * Mc * D_MODEL;

        quant_kernel<<<Mc * D_MODEL / 1024, 256, 0, stream>>>(xc, qx, sxT, Mc, D_MODEL / GSIZE);

        dim3 g12(D_FF / 128, Mc / 128);
        gemm_bit12<<<g12, 256, 0, stream>>>(qx, sxT, w1b, w2b, wsum, qh, shT,
                                            D_MODEL / GSIZE, Mc);

        dim3 g3(D_MODEL / 128, Mc / 128, S);
        gemm_bit3<<<g3, 256, 0, stream>>>(qh, shT, w3b, wsum + 2, outc,
                                          D_MODEL, D_FF / GSIZE, Mc, gPer);
    }
}

// Round 2
// 1419.252 us; speedup vs baseline: 1.8492x; 1.8492x over previous
//
#include <hip/hip_runtime.h>
#include <hip/hip_bf16.h>
#include <math.h>

// Problem constants
#define D_MODEL 2048
#define D_FF    8192
#define MTOK    8192        // 4*2048 tokens
#define GSIZE   64
#define QBF     127.0f
#define EPSQ    1e-5f
#define W_NUMEL (D_FF * D_MODEL)        // 16,777,216 for all three weights
#define W_INV_NUMEL (1.0f / 16777216.0f)
#define NWAVE_PACK (W_NUMEL / 8 / 64)   // 32768 waves per wpack dispatch

typedef unsigned short u16;
typedef __attribute__((ext_vector_type(8))) short short8;   // 8 bf16 (A/B frag)
typedef __attribute__((ext_vector_type(4))) float f32x4;    // C/D frag
typedef __attribute__((ext_vector_type(4))) unsigned int u32x4;
typedef __attribute__((ext_vector_type(4))) unsigned short u16x4;

// Async global->LDS, 16B per lane. LDS image must be linear in lane order.
__device__ __forceinline__ void gload_lds16(const void* g, void* l) {
    __builtin_amdgcn_global_load_lds(
        (const __attribute__((address_space(1))) unsigned int*)g,
        (__attribute__((address_space(3))) unsigned int*)l, 16, 0, 0);
}

// Bijective XCD-chunked block swizzle (m204): hw-id orig -> logical tile id.
__device__ __forceinline__ void xcd_swizzle(int& bx, int& by, int gx, int gy) {
    int nwg  = gx * gy;
    int orig = by * gx + bx;
    int q = nwg >> 3, r = nwg & 7;
    int xcd = orig & 7, loc = orig >> 3;
    int swz = (xcd < r ? xcd * (q + 1) : r * (q + 1) + (xcd - r) * q) + loc;
    bx = swz % gx;
    by = swz / gx;
}

// Tile-swizzled element offset (u16 units) for logical (tileIdx, r, k):
//   off = tileIdx*8192 + r*64 + ((c ^ (r&7))*8) + j,  c=(k&63)>>3, j=k&7
// 128x64 bf16 tile = contiguous 16 KB block; XOR swizzle makes ds_read_b128
// fragment loads bank-conflict-free.

// ------- weight pack: fp32 [N,K] -> +-1 bf16 swizzled tiles --------------
// Per-wave |w| partial sums go to a scratch array (NO same-address atomics:
// round-1 showed 32768 same-address atomicAdds serialize at ~13ns each
// -> 422us). A tiny reduce kernel sums them afterwards.
__global__ void wpack_kernel(const float* __restrict__ W, u16* __restrict__ Wb,
                             float* __restrict__ partial, int N, int K) {
    const int Gk  = K >> 6;
    const int cpr = K >> 3;                 // 8-elem chunks per row
    int idx = blockIdx.x * blockDim.x + threadIdx.x;   // grid is exact
    int row = idx / cpr;
    int ck  = idx - row * cpr;
    int k0  = ck << 3;
    const float* src = W + (size_t)row * K + k0;
    f32x4 w0 = *(const f32x4*)src;
    f32x4 w1 = *(const f32x4*)(src + 4);
    unsigned hw[8];
    float s = 0.f;
    #pragma unroll
    for (int i = 0; i < 8; ++i) {
        float wv = (i < 4) ? w0[i] : w1[i - 4];
        s += fabsf(wv);
        hw[i] = (wv == 0.f) ? 0u : (0x3F80u | ((__float_as_uint(wv) >> 16) & 0x8000u));
    }
    u32x4 o;
    #pragma unroll
    for (int p = 0; p < 4; ++p) o[p] = hw[2 * p] | (hw[2 * p + 1] << 16);
    int nt = row >> 7, r = row & 127;
    int g = k0 >> 6, c8 = (k0 & 63) >> 3;
    size_t dst = ((size_t)(nt * Gk + g) << 13) + (size_t)r * 64 + (size_t)((c8 ^ (r & 7)) << 3);
    *(u32x4*)(Wb + dst) = o;
    #pragma unroll
    for (int off = 32; off > 0; off >>= 1) s += __shfl_xor(s, off);
    if ((threadIdx.x & 63) == 0) partial[idx >> 6] = s;   // contention-free
}

// Sum 3 partial arrays -> wsum[0..2]. Grid = 3 blocks of 256.
__global__ void wsum_reduce(const float* __restrict__ partial, float* __restrict__ wsum) {
    __shared__ float red[4];
    const float* p = partial + (size_t)blockIdx.x * NWAVE_PACK;
    float s = 0.f;
    for (int i = threadIdx.x; i < NWAVE_PACK; i += 256) s += p[i];
    #pragma unroll
    for (int off = 32; off > 0; off >>= 1) s += __shfl_xor(s, off);
    if ((threadIdx.x & 63) == 0) red[threadIdx.x >> 6] = s;
    __syncthreads();
    if (threadIdx.x == 0) wsum[blockIdx.x] = red[0] + red[1] + red[2] + red[3];
}

// ---------------- per-group activation quant (swizzled tile output) ------
// X: [M, K=Gk*64] fp32 -> Q int-valued-bf16 swizzled tiles, SdivT[g][M]=s/127
__global__ void quant_kernel(const float* __restrict__ X, u16* __restrict__ Q,
                             float* __restrict__ SdivT, int M, int Gk) {
    const int K = Gk << 6;
    const int lane = threadIdx.x & 63;
    const int segs = K >> 8;
    int widx = (blockIdx.x * blockDim.x + threadIdx.x) >> 6;
    if (widx >= M * segs) return;
    int row = widx / segs;
    int seg = widx - row * segs;
    int k0 = (seg << 8) + lane * 4;
    f32x4 v = *(const f32x4*)(X + (size_t)row * K + k0);
    float a = fmaxf(fmaxf(fabsf(v[0]), fabsf(v[1])), fmaxf(fabsf(v[2]), fabsf(v[3])));
    a = fmaxf(a, __shfl_xor(a, 1));
    a = fmaxf(a, __shfl_xor(a, 2));
    a = fmaxf(a, __shfl_xor(a, 4));
    a = fmaxf(a, __shfl_xor(a, 8));          // max over the 16-lane (64-elem) group
    float s = fmaxf(a, EPSQ);
    float rinv = QBF / s;
    u16x4 qo;
    #pragma unroll
    for (int c = 0; c < 4; ++c) {
        float q = rintf(fminf(fmaxf(v[c] * rinv, -QBF), QBF));
        qo[c] = (u16)(__float_as_uint(q) >> 16);                 // exact int bf16
    }
    int mt = row >> 7, r = row & 127;
    int gi = k0 >> 6;
    int c8 = (k0 & 63) >> 3;
    int j0 = k0 & 7;
    size_t dst = ((size_t)(mt * Gk + gi) << 13) + (size_t)r * 64
               + (size_t)((c8 ^ (r & 7)) << 3) + j0;
    *(u16x4*)(Q + dst) = qo;
    if ((lane & 15) == 0) SdivT[(size_t)gi * M + row] = s / QBF;
}

// ------------- fused up-projection: GEMM1+GEMM2 + silu*mul + requant -----
__global__ __launch_bounds__(256, 2)
void gemm_bit12(const u16* __restrict__ Aq, const float* __restrict__ SdivT,
                const u16* __restrict__ W1b, const u16* __restrict__ W2b,
                const float* __restrict__ wsum,
                u16* __restrict__ Qh, float* __restrict__ ShT,
                int G, int Mtot) {
    __shared__ __align__(16) u16 lsm[3 * 8192];   // lA | lB1 | lB2 (reused by epilogue)
    __shared__ __align__(16) float lS[128];
    u16* lA  = lsm;
    u16* lB1 = lsm + 8192;
    u16* lB2 = lsm + 16384;

    const int tid  = threadIdx.x;
    const int lane = tid & 63;
    const int wid  = tid >> 6;
    const int quad = lane >> 4;
    const int l16  = lane & 15;
    const int wm = (wid & 1) * 64;
    const int wn = (wid >> 1) * 64;

    int bx = blockIdx.x, by = blockIdx.y;
    xcd_swizzle(bx, by, gridDim.x, gridDim.y);
    const int m0 = by * 128;

    const char* gA  = (const char*)(Aq  + ((size_t)by * G << 13));
    const char* gB1 = (const char*)(W1b + ((size_t)bx * G << 13));
    const char* gB2 = (const char*)(W2b + ((size_t)bx * G << 13));
    char* dA  = (char*)lA  + tid * 16;
    char* dB1 = (char*)lB1 + tid * 16;
    char* dB2 = (char*)lB2 + tid * 16;

    f32x4 acc1[4][4], acc2[4][4];
    #pragma unroll
    for (int i = 0; i < 4; ++i)
        #pragma unroll
        for (int j = 0; j < 4; ++j) {
            acc1[i][j] = (f32x4){0.f, 0.f, 0.f, 0.f};
            acc2[i][j] = (f32x4){0.f, 0.f, 0.f, 0.f};
        }
    const f32x4 czero = {0.f, 0.f, 0.f, 0.f};

    for (int g = 0; g < G; ++g) {
        __syncthreads();                       // prior iter done reading LDS
        const char* sA  = gA  + ((size_t)g << 14);   // 16 KB per tile
        const char* sB1 = gB1 + ((size_t)g << 14);
        const char* sB2 = gB2 + ((size_t)g << 14);
        #pragma unroll
        for (int i = 0; i < 4; ++i) gload_lds16(sA  + tid * 16 + i * 4096, dA  + i * 4096);
        #pragma unroll
        for (int i = 0; i < 4; ++i) gload_lds16(sB1 + tid * 16 + i * 4096, dB1 + i * 4096);
        #pragma unroll
        for (int i = 0; i < 4; ++i) gload_lds16(sB2 + tid * 16 + i * 4096, dB2 + i * 4096);
        if (tid < 128) lS[tid] = SdivT[(size_t)g * Mtot + m0 + tid];
        __syncthreads();                       // drains vmcnt -> tiles visible

        short8 a[4][2];
        #pragma unroll
        for (int mi = 0; mi < 4; ++mi)
            #pragma unroll
            for (int ks = 0; ks < 2; ++ks) {
                int r = wm + mi * 16 + l16;
                int c = ks * 4 + quad;
                a[mi][ks] = *(const short8*)(lA + r * 64 + ((c ^ (r & 7)) << 3));
            }
        f32x4 sf[4];
        #pragma unroll
        for (int mi = 0; mi < 4; ++mi)
            sf[mi] = *(const f32x4*)(lS + wm + mi * 16 + quad * 4);

        #pragma unroll
        for (int ni = 0; ni < 4; ++ni) {
            int rb = wn + ni * 16 + l16;
            int sw0 = ((quad)     ^ (rb & 7)) << 3;
            int sw1 = ((4 + quad) ^ (rb & 7)) << 3;
            short8 b10 = *(const short8*)(lB1 + rb * 64 + sw0);
            short8 b11 = *(const short8*)(lB1 + rb * 64 + sw1);
            short8 b20 = *(const short8*)(lB2 + rb * 64 + sw0);
            short8 b21 = *(const short8*)(lB2 + rb * 64 + sw1);
            #pragma unroll
            for (int mi = 0; mi < 4; ++mi) {
                f32x4 t = __builtin_amdgcn_mfma_f32_16x16x32_bf16(a[mi][0], b10, czero, 0, 0, 0);
                t = __builtin_amdgcn_mfma_f32_16x16x32_bf16(a[mi][1], b11, t, 0, 0, 0);
                acc1[mi][ni] += t * sf[mi];
                f32x4 u = __builtin_amdgcn_mfma_f32_16x16x32_bf16(a[mi][0], b20, czero, 0, 0, 0);
                u = __builtin_amdgcn_mfma_f32_16x16x32_bf16(a[mi][1], b21, u, 0, 0, 0);
                acc2[mi][ni] += u * sf[mi];
            }
        }
    }

    // ---- epilogue: h = silu(y1)*y2, per-64-group quant, swizzled tile out ----
    const float ws1 = wsum[0] * W_INV_NUMEL;
    const float ws2 = wsum[1] * W_INV_NUMEL;
    const int gl    = wn >> 6;                 // which of the 2 groups in this block
    const int gbase = bx * 2;                  // global d_ff group base (128 cols/block)
    __syncthreads();                           // done with lA/lB*, reuse as staging
    #pragma unroll
    for (int mi = 0; mi < 4; ++mi) {
        #pragma unroll
        for (int rr = 0; rr < 4; ++rr) {
            float h[4];
            #pragma unroll
            for (int ni = 0; ni < 4; ++ni) {
                float y1 = acc1[mi][ni][rr] * ws1;
                float y2 = acc2[mi][ni][rr] * ws2;
                h[ni] = (y1 / (1.f + expf(-y1))) * y2;   // silu(y1)*y2
            }
            float am = fmaxf(fmaxf(fabsf(h[0]), fabsf(h[1])), fmaxf(fabsf(h[2]), fabsf(h[3])));
            am = fmaxf(am, __shfl_xor(am, 1));
            am = fmaxf(am, __shfl_xor(am, 2));
            am = fmaxf(am, __shfl_xor(am, 4));
            am = fmaxf(am, __shfl_xor(am, 8));   // absmax over 4 ni x 16 lanes = 64 cols
            float s = fmaxf(am, EPSQ);
            float rinv = QBF / s;
            int rblk = wm + mi * 16 + quad * 4 + rr;
            #pragma unroll
            for (int ni = 0; ni < 4; ++ni) {
                float qv = rintf(fminf(fmaxf(h[ni] * rinv, -QBF), QBF));
                int k = ni * 16 + l16;
                int c8 = k >> 3;
                lsm[gl * 8192 + rblk * 64 + ((c8 ^ (rblk & 7)) << 3) + (k & 7)]
                    = (u16)(__float_as_uint(qv) >> 16);
            }
            if (l16 == 0) ShT[(size_t)(gbase + gl) * Mtot + m0 + rblk] = s / QBF;
        }
    }
    __syncthreads();
    // two 16 KB tiles (groups gbase, gbase+1) are contiguous in Qh
    size_t base = ((size_t)by * 128 + (size_t)gbase) << 13;   // u16 elements; Gff=128
    u32x4* dst = (u32x4*)(Qh + base);
    const u32x4* src = (const u32x4*)lsm;
    #pragma unroll
    for (int i = 0; i < 8; ++i) dst[tid + i * 256] = src[tid + i * 256];
}

// ---------------- down-projection: (split-K) bit-GEMM --------------------
// gridDim.z == 1 -> plain stores; > 1 -> fp32 atomicAdd onto zeroed output.
__global__ __launch_bounds__(256, 3)
void gemm_bit3(const u16* __restrict__ Aq, const float* __restrict__ SdivT,
               const u16* __restrict__ Wb, const float* __restrict__ wsum,
               float* __restrict__ Y, int N, int G, int Mtot, int gPer) {
    __shared__ __align__(16) u16  lA[8192];
    __shared__ __align__(16) u16  lB[8192];
    __shared__ __align__(16) float lS[128];

    const int tid  = threadIdx.x;
    const int lane = tid & 63;
    const int wid  = tid >> 6;
    const int quad = lane >> 4;
    const int l16  = lane & 15;
    const int wm = (wid & 1) * 64;
    const int wn = (wid >> 1) * 64;

    int bx = blockIdx.x, by = blockIdx.y;
    xcd_swizzle(bx, by, gridDim.x, gridDim.y);
    const int m0 = by * 128;
    const int n0 = bx * 128;
    const int g0 = blockIdx.z * gPer;

    const char* gA = (const char*)(Aq + ((size_t)by * G << 13));
    const char* gB = (const char*)(Wb + ((size_t)bx * G << 13));
    char* dA = (char*)lA + tid * 16;
    char* dB = (char*)lB + tid * 16;

    f32x4 acc[4][4];
    #pragma unroll
    for (int i = 0; i < 4; ++i)
        #pragma unroll
        for (int j = 0; j < 4; ++j) acc[i][j] = (f32x4){0.f, 0.f, 0.f, 0.f};
    const f32x4 czero = {0.f, 0.f, 0.f, 0.f};

    for (int g = g0; g < g0 + gPer; ++g) {
        __syncthreads();
        const char* sA = gA + ((size_t)g << 14);
        const char* sB = gB + ((size_t)g << 14);
        #pragma unroll
        for (int i = 0; i < 4; ++i) gload_lds16(sA + tid * 16 + i * 4096, dA + i * 4096);
        #pragma unroll
        for (int i = 0; i < 4; ++i) gload_lds16(sB + tid * 16 + i * 4096, dB + i * 4096);
        if (tid < 128) lS[tid] = SdivT[(size_t)g * Mtot + m0 + tid];
        __syncthreads();

        short8 a[4][2];
        #pragma unroll
        for (int mi = 0; mi < 4; ++mi)
            #pragma unroll
            for (int ks = 0; ks < 2; ++ks) {
                int r = wm + mi * 16 + l16;
                int c = ks * 4 + quad;
                a[mi][ks] = *(const short8*)(lA + r * 64 + ((c ^ (r & 7)) << 3));
            }
        f32x4 sf[4];
        #pragma unroll
        for (int mi = 0; mi < 4; ++mi)
            sf[mi] = *(const f32x4*)(lS + wm + mi * 16 + quad * 4);

        #pragma unroll
        for (int ni = 0; ni < 4; ++ni) {
            int rb = wn + ni * 16 + l16;
            short8 b0 = *(const short8*)(lB + rb * 64 + ((quad ^ (rb & 7)) << 3));
            short8 b1 = *(const short8*)(lB + rb * 64 + (((4 + quad) ^ (rb & 7)) << 3));
            #pragma unroll
            for (int mi = 0; mi < 4; ++mi) {
                f32x4 t = __builtin_amdgcn_mfma_f32_16x16x32_bf16(a[mi][0], b0, czero, 0, 0, 0);
                t = __builtin_amdgcn_mfma_f32_16x16x32_bf16(a[mi][1], b1, t, 0, 0, 0);
                acc[mi][ni] += t * sf[mi];
            }
        }
    }

    const float wsc = wsum[0] * W_INV_NUMEL;   // mean|w3| (wsum pre-offset by caller)
    #pragma unroll
    for (int mi = 0; mi < 4; ++mi) {
        #pragma unroll
        for (int ni = 0; ni < 4; ++ni) {
            int col = n0 + wn + ni * 16 + l16;
            #pragma unroll
            for (int r = 0; r < 4; ++r) {
                int row = m0 + wm + mi * 16 + quad * 4 + r;
                size_t o = (size_t)row * N + col;
                float v = acc[mi][ni][r] * wsc;
                if (gridDim.z == 1) Y[o] = v;
                else atomicAdd(&Y[o], v);
            }
        }
    }
}

extern "C" void kernel_launch(void* const* d_in, const int* in_sizes, int n_in,
                              void* d_out, int out_size, void* d_ws, size_t ws_size,
                              hipStream_t stream) {
    const float* x  = (const float*)d_in[0];
    const float* w1 = (const float*)d_in[1];
    const float* w2 = (const float*)d_in[2];
    const float* w3 = (const float*)d_in[3];
    float* out = (float*)d_out;

    // ---- workspace layout: packed weights (fixed) + chunked activations ----
    char* ws = (char*)d_ws;
    const size_t wbBytes = (size_t)W_NUMEL * 2;        // 32 MB per packed weight
    float* wsum = (float*)ws;
    char* p = ws + 256;
    u16* w1b = (u16*)p;  p += wbBytes;
    u16* w2b = (u16*)p;  p += wbBytes;
    u16* w3b = (u16*)p;  p += wbBytes;
    float* partial = (float*)p;  p += (size_t)3 * NWAVE_PACK * 4;   // 384 KB
    size_t fixed = (size_t)(p - ws);

    // per-token: qx 4096 + sxT 128 + qh 16384 + shT 512 = 21,120 B (no fp32 h)
    const size_t perTok = (size_t)D_MODEL * 2 + 32 * 4 + (size_t)D_FF * 2 + 128 * 4;
    int Mc = 1024;
    for (int cand = MTOK; cand >= 1024; cand >>= 1) {
        if (fixed + perTok * (size_t)cand <= ws_size) { Mc = cand; break; }
    }
    const int nChunks = MTOK / Mc;

    u16*   qx  = (u16*)p;         p += (size_t)Mc * D_MODEL * 2;
    float* sxT = (float*)p;       p += (size_t)Mc * 32 * 4;      // [32][Mc]
    u16*   qh  = (u16*)p;         p += (size_t)Mc * D_FF * 2;
    float* shT = (float*)p;                                      // [128][Mc]

    // pack weights + contention-free |w| partials (weights read exactly once)
    wpack_kernel<<<W_NUMEL / 8 / 256, 256, 0, stream>>>(w1, w1b, partial + 0 * NWAVE_PACK, D_FF, D_MODEL);
    wpack_kernel<<<W_NUMEL / 8 / 256, 256, 0, stream>>>(w2, w2b, partial + 1 * NWAVE_PACK, D_FF, D_MODEL);
    wpack_kernel<<<W_NUMEL / 8 / 256, 256, 0, stream>>>(w3, w3b, partial + 2 * NWAVE_PACK, D_MODEL, D_FF);
    wsum_reduce<<<3, 256, 0, stream>>>(partial, wsum);

    // split-K factor for the down-projection: keep >= ~1024 blocks resident
    const int S = MTOK / Mc;                    // 1,2,4,8 — divides 128
    const int gPer = (D_FF / GSIZE) / S;
    if (S > 1) (void)hipMemsetAsync(out, 0, (size_t)out_size, stream);

    for (int c = 0; c < nChunks; ++c) {
        const float* xc = x + (size_t)c * Mc * D_MODEL;
        float* outc     = out + (size_t)c * Mc * D_MODEL;

        quant_kernel<<<Mc * D_MODEL / 1024, 256, 0, stream>>>(xc, qx, sxT, Mc, D_MODEL / GSIZE);

        dim3 g12(D_FF / 128, Mc / 128);
        gemm_bit12<<<g12, 256, 0, stream>>>(qx, sxT, w1b, w2b, wsum, qh, shT,
                                            D_MODEL / GSIZE, Mc);

        dim3 g3(D_MODEL / 128, Mc / 128, S);
        gemm_bit3<<<g3, 256, 0, stream>>>(qh, shT, w3b, wsum + 2, outc,
                                          D_MODEL, D_FF / GSIZE, Mc, gPer);
    }
}